// Round 12
// baseline (108.618 us; speedup 1.0000x reference)
//
#include <hip/hip_runtime.h>
#include <hip/hip_bf16.h>

#define BB 16
#define LL 2048
#define DD 512
#define BL (BB*LL)
#define RADIUS 15
#define CF 1.25331414f   /* sqrt(2*pi)/2 */
#define NSL 12           /* j-slices: live blocks = 16*12*nIt ~ 1630 -> ~6.4/CU */
#define NII 16           /* i-instance slots (dead ones exit fast) */

typedef __attribute__((ext_vector_type(8))) short short8_t;
typedef __attribute__((ext_vector_type(4))) float f32x4;
typedef __attribute__((ext_vector_type(2))) long long2_t;

static __device__ __forceinline__ unsigned short f2bf(float x){
  unsigned int u = __float_as_uint(x);
  return (unsigned short)((u + 0x7fffu + ((u >> 16) & 1u)) >> 16);  // RNE
}

static __device__ __forceinline__ void gld_lds16(const void* g, void* l){
  __builtin_amdgcn_global_load_lds(
      (const __attribute__((address_space(1))) unsigned int*)g,
      (__attribute__((address_space(3))) unsigned int*)l, 16, 0, 0);
}

// ---- f32 -> fp8 e4m3fn (OCP), RNE, saturating ----
#if __has_builtin(__builtin_amdgcn_cvt_pk_fp8_f32)
static __device__ __forceinline__ long f2fp8x8(float4 x0, float4 x1){
  int w0 = __builtin_amdgcn_cvt_pk_fp8_f32(x0.x, x0.y, 0, false);
  w0     = __builtin_amdgcn_cvt_pk_fp8_f32(x0.z, x0.w, w0, true);
  int w1 = __builtin_amdgcn_cvt_pk_fp8_f32(x1.x, x1.y, 0, false);
  w1     = __builtin_amdgcn_cvt_pk_fp8_f32(x1.z, x1.w, w1, true);
  return ((long)(unsigned)w1 << 32) | (unsigned)w0;
}
#else
static __device__ __forceinline__ unsigned f2fp8_1(float xf){
  unsigned x = __float_as_uint(xf);
  unsigned s = (x >> 24) & 0x80u;
  unsigned ax = x & 0x7fffffffu;
  if (ax >= 0x43e80000u) return s | 0x7eu;
  if (ax <  0x3a800000u) return s;
  unsigned exp = ax >> 23;
  if (exp <= 120){
    unsigned man = (ax & 0x7fffffu) | 0x800000u;
    int rsh = 141 - (int)exp;
    unsigned keep = man >> rsh;
    unsigned rem  = man & ((1u << rsh) - 1u);
    unsigned half = 1u << (rsh - 1);
    keep += (rem > half || (rem == half && (keep & 1u)));
    return s | keep;
  }
  unsigned keep = ax >> 20;
  unsigned rem  = ax & 0xfffffu;
  keep += (rem > 0x80000u || (rem == 0x80000u && (keep & 1u)));
  int code = (int)keep - (120 << 3);
  if (code >= 0x7f) code = 0x7e;
  return s | (unsigned)code;
}
static __device__ __forceinline__ long f2fp8x8(float4 x0, float4 x1){
  unsigned long o = 0;
  o |= (unsigned long)f2fp8_1(x0.x);
  o |= (unsigned long)f2fp8_1(x0.y) << 8;
  o |= (unsigned long)f2fp8_1(x0.z) << 16;
  o |= (unsigned long)f2fp8_1(x0.w) << 24;
  o |= (unsigned long)f2fp8_1(x1.x) << 32;
  o |= (unsigned long)f2fp8_1(x1.y) << 40;
  o |= (unsigned long)f2fp8_1(x1.z) << 48;
  o |= (unsigned long)f2fp8_1(x1.w) << 56;
  return (long)o;
}
#endif

// ============================ fast path (fp8) ============================
// p8 / q8 fragment-major per batch, BANK-SWIZZLED:
//   chunk(kb, row16tile) = 512 B at  b*LL*DD + (kb*LL + tile*16)*32
//   within chunk: (row r, group kg) -> (r&15)*32 + (kg ^ ((r>>2)&3))*8
// reader lane (col,kg) uses byte col*32 + (kg^(col>>2))*8 -> uniform 2/bank.

__global__ void mcount_kernel(const int* __restrict__ mask, int* __restrict__ mout){
  int b = blockIdx.x;
  int s = 0;
  for (int j = threadIdx.x; j < LL; j += 256) s += (mask[(size_t)b*LL + j] > 0) ? 1 : 0;
  __shared__ int sred[256];
  sred[threadIdx.x] = s; __syncthreads();
  for (int k = 128; k; k >>= 1){
    if (threadIdx.x < k) sred[threadIdx.x] += sred[threadIdx.x + k];
    __syncthreads();
  }
  if (threadIdx.x == 0) mout[b] = sred[0];
}

// normalize rows -> fp8 fragment-major (swizzled), 4 rows per wave.
__global__ __launch_bounds__(256) void precvt(const float* __restrict__ embs,
                                              const float* __restrict__ clip,
                                              const int* __restrict__ mcnt,
                                              unsigned char* __restrict__ p8,
                                              unsigned char* __restrict__ q8){
  const int lane = threadIdx.x & 63;
  const int g    = lane >> 4;                  // row within 4-row group
  const int c    = lane & 15;                  // kb owned by this lane
  const int base = blockIdx.x * 16 + (threadIdx.x >> 6) * 4;   // 4-row group start
  const int gw   = base + g;                   // this lane's row id in [0, 2*BL)

  const float* src; unsigned char* dst; int r, b; bool isP;
  if (gw < BL){ isP = true;  b = gw >> 11; r = gw & 2047;
                src = embs + (size_t)gw * DD; dst = p8 + (size_t)b * LL * DD; }
  else        { isP = false; int g2 = gw - BL; b = g2 >> 11; r = g2 & 2047;
                src = clip + (size_t)g2 * DD; dst = q8 + (size_t)b * LL * DD; }
  const int M   = mcnt[b];
  const int RND = isP ? ((M + 127) & ~127) : ((M + 15) & ~15);
  if (r >= RND) return;                        // wave-uniform (4 rows, same r>>2)

  float4 v[8];
  #pragma unroll
  for (int k = 0; k < 8; ++k) v[k] = *(const float4*)(src + c * 32 + k * 4);
  float ss = 0.f;
  #pragma unroll
  for (int k = 0; k < 8; ++k)
    ss += v[k].x*v[k].x + v[k].y*v[k].y + v[k].z*v[k].z + v[k].w*v[k].w;
  #pragma unroll
  for (int m = 1; m < 16; m <<= 1) ss += __shfl_xor(ss, m, 64);   // 16-lane group
  const float s = 1.0f / fmaxf(sqrtf(ss), 1e-12f);
  #pragma unroll
  for (int k = 0; k < 8; ++k){
    v[k].x *= s; v[k].y *= s; v[k].z *= s; v[k].w *= s;
  }
  const long o0 = f2fp8x8(v[0], v[1]);         // kg 0
  const long o1 = f2fp8x8(v[2], v[3]);         // kg 1
  const long o2 = f2fp8x8(v[4], v[5]);         // kg 2
  const long o3 = f2fp8x8(v[6], v[7]);         // kg 3
  const int xr = (r >> 2) & 3;                 // wave-uniform -> static permutes
  long2_t lo, hi;
  switch (xr){
    case 0: lo = (long2_t){o0, o1}; hi = (long2_t){o2, o3}; break;
    case 1: lo = (long2_t){o1, o0}; hi = (long2_t){o3, o2}; break;
    case 2: lo = (long2_t){o2, o3}; hi = (long2_t){o0, o1}; break;
    default:lo = (long2_t){o3, o2}; hi = (long2_t){o1, o0}; break;
  }
  unsigned char* wb = dst + ((size_t)(c * LL + r) << 5);
  *(long2_t*)(wb)      = lo;
  *(long2_t*)(wb + 16) = hi;
}

// 4 waves/block, ONE 128-row i-tile per block; 16-col j-tiles, 2x8KB LDS dbuf.
// 6 blocks/CU: block-level TLP covers the stage drain + barrier stalls.
__global__ __launch_bounds__(256, 6) void gram11(
    const unsigned char* __restrict__ p8, const unsigned char* __restrict__ q8,
    const int* __restrict__ mcnt, float* __restrict__ part /* [BB][LL][NSL] float4 */)
{
  const int bid = blockIdx.x;                 // 16 * NSL * NII = 3072
  const int xcd = bid & 7;
  const int b   = (xcd << 1) | ((bid >> 3) & 1);   // batch pinned to XCD
  const int ii  = (bid >> 4) & (NII - 1);          // i-tile (fast-varying)
  const int js  = bid >> 8;                        // j-slice [0,NSL)
  const int M   = mcnt[b];
  const int nIt = (M + 127) >> 7;
  if (ii >= nIt) return;                           // dead block: exits fast

  __shared__ alignas(16) unsigned char bsm[2][8192];   // 2 x 8 KB fp8 B-tiles
  __shared__ float gt[RADIUS + 1];

  const int tid  = threadIdx.x;
  const int wave = tid >> 6;
  const int lane = tid & 63;
  const int col  = lane & 15;
  const int kg   = lane >> 4;
  const int kswz = (kg ^ (col >> 2)) << 3;     // bank-swizzled 8B slot

  const unsigned char* pb = p8 + (size_t)b * LL * DD;
  const unsigned char* qb = q8 + (size_t)b * LL * DD;
  const int njt = (M + 15) >> 4;
  const int S   = (njt > js) ? ((njt - js + NSL - 1) / NSL) : 0;
  if (S == 0) return;

  if (tid <= RADIUS)
    gt[tid] = expm1f(CF * __expf(-(float)(tid * tid) * 0.125f));
  __syncthreads();

  #define STAGE(BF, JT) do {                                                     \
    const int _j0 = (JT) << 4;                                                   \
    _Pragma("unroll")                                                            \
    for (int u = 0; u < 2; ++u){                                                 \
      const int _kb0 = (wave << 1) + (u << 3);                                   \
      gld_lds16(qb + ((size_t)((_kb0 + (lane >> 5)) * LL + _j0) << 5)            \
                   + ((lane & 31) << 4),                                         \
                (void*)&bsm[BF][_kb0 << 9]);                                     \
    }                                                                            \
  } while (0)

  const int iw = (ii << 7) + (wave << 5);      // this wave's 32-row stripe base

  // A fragments: 2 stripes x 16 kb, 2 VGPRs each
  long a0[16], a1[16];
  #pragma unroll
  for (int kb = 0; kb < 16; ++kb){
    a0[kb] = *(const long*)(pb + ((size_t)(kb * LL + iw      + col) << 5) + kswz);
    a1[kb] = *(const long*)(pb + ((size_t)(kb * LL + iw + 16 + col) << 5) + kswz);
  }

  float es0[4]={0,0,0,0}, ls0[4]={0,0,0,0}, bg0[4]={0,0,0,0};
  float es1[4]={0,0,0,0}, ls1[4]={0,0,0,0}, bg1[4]={0,0,0,0};

  STAGE(0, js);
  asm volatile("s_waitcnt vmcnt(0)" ::: "memory");
  __builtin_amdgcn_s_barrier();
  __builtin_amdgcn_sched_barrier(0);

  int buf = 0;
  for (int s = 0; s < S; ++s){
    if (s + 1 < S) STAGE(buf ^ 1, js + NSL * (s + 1));   // prefetch next tile

    const int j0 = (js + NSL * s) << 4;
    f32x4 c0 = {0.f,0.f,0.f,0.f}, c1 = {0.f,0.f,0.f,0.f};
    const unsigned char* lb = &bsm[buf][(col << 5) + kswz];
    #pragma unroll
    for (int kb = 0; kb < 16; ++kb){
      long bf8 = *(const long*)(lb + (kb << 9));    // ds_read_b64, 2/bank
      c0 = __builtin_amdgcn_mfma_f32_16x16x32_fp8_fp8(a0[kb], bf8, c0, 0, 0, 0);
      c1 = __builtin_amdgcn_mfma_f32_16x16x32_fp8_fp8(a1[kb], bf8, c1, 0, 0, 0);
    }
    const int j = j0 + col;
    const bool bandw = (j0 + 15 >= iw - RADIUS) && (j0 <= iw + 31 + RADIUS);
    if (j < M){
      const int dt0 = j - iw - (kg << 2);
      #pragma unroll
      for (int r = 0; r < 4; ++r){
        float lg = c0[r];                      // logits[iw + kg*4 + r][j]
        float lh = c1[r];                      // logits[iw+16 + kg*4 + r][j]
        es0[r] += __expf(lg); ls0[r] += lg;
        es1[r] += __expf(lh); ls1[r] += lh;
        if (bandw){
          int d = dt0 - r; int ad = d < 0 ? -d : d;
          if (ad <= RADIUS) bg0[r] += gt[ad] * lg;
          int d1 = dt0 - 16 - r; int ad1 = d1 < 0 ? -d1 : d1;
          if (ad1 <= RADIUS) bg1[r] += gt[ad1] * lh;
        }
      }
    }
    asm volatile("s_waitcnt vmcnt(0)" ::: "memory");   // next tile landed
    __builtin_amdgcn_s_barrier();                      // all waves done with buf
    __builtin_amdgcn_sched_barrier(0);
    buf ^= 1;
  }
  #undef STAGE

  #pragma unroll
  for (int m = 1; m < 16; m <<= 1){
    #pragma unroll
    for (int r = 0; r < 4; ++r){
      es0[r] += __shfl_xor(es0[r], m, 64); es1[r] += __shfl_xor(es1[r], m, 64);
      ls0[r] += __shfl_xor(ls0[r], m, 64); ls1[r] += __shfl_xor(ls1[r], m, 64);
      bg0[r] += __shfl_xor(bg0[r], m, 64); bg1[r] += __shfl_xor(bg1[r], m, 64);
    }
  }
  if (col == 0){
    #pragma unroll
    for (int r = 0; r < 4; ++r){
      int ia = iw + (kg << 2) + r;
      *(float4*)&part[(((size_t)b * LL + ia) * NSL + js) * 4] = make_float4(es0[r], ls0[r], bg0[r], 0.f);
      int ib = ia + 16;
      *(float4*)&part[(((size_t)b * LL + ib) * NSL + js) * 4] = make_float4(es1[r], ls1[r], bg1[r], 0.f);
    }
  }
}

// per-batch row-sum epilogue with analytic Zt/U prefix tables
__global__ __launch_bounds__(256) void finalize1(const float* __restrict__ part,
                                                 const int* __restrict__ mcnt,
                                                 float* __restrict__ psum){
  const int b = blockIdx.x;
  const int M = mcnt[b];
  __shared__ float e1s[16], tts[16], S1[16], TT[16], red[256];
  const int tid = threadIdx.x;
  if (tid < 16){
    float u  = CF * __expf(-(float)(tid * tid) * 0.125f);
    float eu = __expf(u);
    e1s[tid] = eu - 1.0f;
    tts[tid] = u * eu;
  }
  __syncthreads();
  if (tid == 0){
    float a = 0.f, c = 0.f;
    S1[0] = 0.f; TT[0] = 0.f;
    for (int d = 1; d <= RADIUS; ++d){ a += e1s[d]; c += tts[d]; S1[d] = a; TT[d] = c; }
  }
  __syncthreads();
  const float e10 = e1s[0], tt0 = tts[0];
  float acc = 0.f;
  for (int i = tid; i < M; i += 256){
    float es = 0.f, ls = 0.f, bg = 0.f;
    #pragma unroll
    for (int h = 0; h < NSL; ++h){
      float4 v = *(const float4*)&part[(((size_t)b * LL + i) * NSL + h) * 4];
      es += v.x; ls += v.y; bg += v.z;
    }
    int rl = i < RADIUS ? i : RADIUS;
    int rr = (M - 1 - i) < RADIUS ? (M - 1 - i) : RADIUS;
    float Zt = (float)M + e10 + S1[rl] + S1[rr];
    float U  = tt0 + TT[rl] + TT[rr];
    acc += (U - ls - bg) / Zt + logf(es) - logf(Zt);
  }
  red[tid] = acc; __syncthreads();
  for (int k = 128; k; k >>= 1){
    if (tid < k) red[tid] += red[tid + k];
    __syncthreads();
  }
  if (tid == 0) psum[b] = red[0] / (float)M;
}

__global__ void finalize2(const float* __restrict__ psum, float* __restrict__ out){
  if (threadIdx.x == 0){
    float a = 0.f;
    for (int b = 0; b < BB; ++b) a += psum[b];
    out[0] = a / (float)BB;
  }
}

// ======================= fallback path (round-1, known good) =======================
#define TI 32
#define TJ 32
#define LSTR 520

__global__ void fb_qnorm(const float* __restrict__ clip, float* __restrict__ invq){
  int row = blockIdx.x;
  const float* p = clip + (size_t)row * DD;
  float4 v = *(const float4*)(p + (threadIdx.x << 2));
  float ss = v.x*v.x + v.y*v.y + v.z*v.z + v.w*v.w;
  for (int m = 32; m; m >>= 1) ss += __shfl_down(ss, m, 64);
  __shared__ float red[2];
  if ((threadIdx.x & 63) == 0) red[threadIdx.x >> 6] = ss;
  __syncthreads();
  if (threadIdx.x == 0)
    invq[row] = 1.0f / fmaxf(sqrtf(red[0] + red[1]), 1e-12f);
}

__global__ __launch_bounds__(256) void fb_main(
    const float* __restrict__ embs, const float* __restrict__ clip,
    const float* __restrict__ invq, const int* __restrict__ mcnt,
    float* __restrict__ row_sums)
{
  const int b  = blockIdx.y;
  const int M  = mcnt[b];
  const int i0 = blockIdx.x * TI;
  if (i0 >= M) return;
  __shared__ alignas(16) unsigned short qlds[TJ * LSTR];
  __shared__ float gtab[RADIUS + 1];
  __shared__ float partials[2][TI][3];
  const int tid  = threadIdx.x;
  const int wave = tid >> 6;
  const int lane = tid & 63;
  const int col  = lane & 15;
  const int kg   = lane >> 4;
  const int isub = wave >> 1;
  const int jsub = wave & 1;
  const int iw   = i0 + isub * 16;
  if (tid <= RADIUS)
    gtab[tid] = expm1f(CF * expf(-(float)(tid * tid) * 0.125f));
  const int arow = iw + col;
  const float* prow = embs + ((size_t)b * LL + arow) * DD;
  float ss = 0.f;
  for (int kb = 0; kb < 16; ++kb){
    float4 x0 = *(const float4*)(prow + kb * 32 + kg * 8);
    float4 x1 = *(const float4*)(prow + kb * 32 + kg * 8 + 4);
    ss += x0.x*x0.x + x0.y*x0.y + x0.z*x0.z + x0.w*x0.w
        + x1.x*x1.x + x1.y*x1.y + x1.z*x1.z + x1.w*x1.w;
  }
  ss += __shfl_xor(ss, 16, 64);
  ss += __shfl_xor(ss, 32, 64);
  const float sp = 1.0f / fmaxf(sqrtf(ss), 1e-12f);
  short8_t afrag[16];
  for (int kb = 0; kb < 16; ++kb){
    float4 x0 = *(const float4*)(prow + kb * 32 + kg * 8);
    float4 x1 = *(const float4*)(prow + kb * 32 + kg * 8 + 4);
    short8_t f;
    f[0]=(short)f2bf(x0.x*sp); f[1]=(short)f2bf(x0.y*sp);
    f[2]=(short)f2bf(x0.z*sp); f[3]=(short)f2bf(x0.w*sp);
    f[4]=(short)f2bf(x1.x*sp); f[5]=(short)f2bf(x1.y*sp);
    f[6]=(short)f2bf(x1.z*sp); f[7]=(short)f2bf(x1.w*sp);
    afrag[kb] = f;
  }
  float es[4]={0,0,0,0}, lsm[4]={0,0,0,0}, bg[4]={0,0,0,0};
  const int nj = (M + TJ - 1) / TJ;
  for (int jt = 0; jt < nj; ++jt){
    const int jb = jt * TJ;
    __syncthreads();
    {
      const float* qbase = clip + ((size_t)b * LL + jb) * DD;
      for (int u = 0; u < 16; ++u){
        int f  = u * 256 + tid;
        int r  = f >> 7, c4 = f & 127;
        int j  = jb + r;
        ushort4 wv = make_ushort4(0,0,0,0);
        if (j < M){
          float s = invq[b * LL + j];
          float4 x = *(const float4*)(qbase + ((size_t)r << 9) + (c4 << 2));
          wv = make_ushort4(f2bf(x.x*s), f2bf(x.y*s), f2bf(x.z*s), f2bf(x.w*s));
        }
        *reinterpret_cast<ushort4*>(&qlds[r * LSTR + (c4 << 2)]) = wv;
      }
    }
    __syncthreads();
    const int j0 = jb + jsub * 16;
    f32x4 acc = {0.f,0.f,0.f,0.f};
    const unsigned short* bbase = &qlds[(jsub * 16 + col) * LSTR + kg * 8];
    #pragma unroll
    for (int kb = 0; kb < 16; ++kb){
      short8_t bfrag = *reinterpret_cast<const short8_t*>(bbase + kb * 32);
      acc = __builtin_amdgcn_mfma_f32_16x16x32_bf16(afrag[kb], bfrag, acc, 0, 0, 0);
    }
    const int j = j0 + col;
    if (j < M){
      const int dt = j - iw - kg * 4;
      #pragma unroll
      for (int r = 0; r < 4; ++r){
        float lg = acc[r];
        es[r]  += expf(lg);
        lsm[r] += lg;
        int d = dt - r; int ad = d < 0 ? -d : d;
        if (ad <= RADIUS) bg[r] += gtab[ad] * lg;
      }
    }
  }
  #pragma unroll
  for (int m = 1; m < 16; m <<= 1){
    #pragma unroll
    for (int r = 0; r < 4; ++r){
      es[r]  += __shfl_xor(es[r],  m, 64);
      lsm[r] += __shfl_xor(lsm[r], m, 64);
      bg[r]  += __shfl_xor(bg[r],  m, 64);
    }
  }
  if (col == 0){
    #pragma unroll
    for (int r = 0; r < 4; ++r){
      int lrow = isub * 16 + kg * 4 + r;
      partials[jsub][lrow][0] = es[r];
      partials[jsub][lrow][1] = lsm[r];
      partials[jsub][lrow][2] = bg[r];
    }
  }
  __syncthreads();
  if (tid < TI){
    int i = i0 + tid;
    if (i < M){
      float esf = partials[0][tid][0] + partials[1][tid][0];
      float lsf = partials[0][tid][1] + partials[1][tid][1];
      float bgf = partials[0][tid][2] + partials[1][tid][2];
      int dlo = (-RADIUS < -i) ? -i : -RADIUS;
      int dhi = (RADIUS > M - 1 - i) ? (M - 1 - i) : RADIUS;
      float Zt = (float)M, U = 0.f;
      for (int d = dlo; d <= dhi; ++d){
        float uu = CF * expf(-(float)(d * d) * 0.125f);
        float eu = expf(uu);
        Zt += eu - 1.0f;
        U  += uu * eu;
      }
      row_sums[(size_t)b * LL + i] = (U - lsf - bgf) / Zt + logf(esf / Zt);
    }
  }
}

__global__ void fb_finalize(const float* __restrict__ row_sums,
                            const int* __restrict__ mcnt, float* __restrict__ out){
  __shared__ float red[256];
  float acc = 0.f;
  for (int b = 0; b < BB; ++b){
    int M = mcnt[b];
    float s = 0.f;
    for (int i = threadIdx.x; i < M; i += 256) s += row_sums[(size_t)b * LL + i];
    red[threadIdx.x] = s; __syncthreads();
    for (int k = 128; k; k >>= 1){
      if (threadIdx.x < k) red[threadIdx.x] += red[threadIdx.x + k];
      __syncthreads();
    }
    if (threadIdx.x == 0) acc += red[0] / (float)M;
    __syncthreads();
  }
  if (threadIdx.x == 0) out[0] = acc / (float)BB;
}

// ================================ launch ================================

extern "C" void kernel_launch(void* const* d_in, const int* in_sizes, int n_in,
                              void* d_out, int out_size, void* d_ws, size_t ws_size,
                              hipStream_t stream) {
  const float* embs = (const float*)d_in[0];
  const float* clip = (const float*)d_in[1];
  const int*   mask = (const int*)d_in[2];
  float* out = (float*)d_out;

  const size_t REQ = (size_t)2 * BL * DD                              // p8 + q8 (fp8)
                   + (size_t)BB * LL * NSL * 4 * sizeof(float)        // partials
                   + 64 * sizeof(float);                              // psum + mcnt
  if (ws_size >= REQ){
    unsigned char* p8 = (unsigned char*)d_ws;
    unsigned char* q8 = p8 + (size_t)BL * DD;
    float* part = (float*)(q8 + (size_t)BL * DD);
    float* psum = part + (size_t)BB * LL * NSL * 4;
    int*   mcnt = (int*)(psum + 16);

    mcount_kernel<<<dim3(BB), 256, 0, stream>>>(mask, mcnt);
    precvt<<<dim3(2 * BL / 16), 256, 0, stream>>>(embs, clip, mcnt, p8, q8);
    gram11<<<dim3(16 * NSL * NII), 256, 0, stream>>>(p8, q8, mcnt, part);
    finalize1<<<dim3(BB), 256, 0, stream>>>(part, mcnt, psum);
    finalize2<<<1, 64, 0, stream>>>(psum, out);
  } else {
    float* ws   = (float*)d_ws;
    float* invq = ws;
    int*   mcnt = (int*)(ws + BL);
    float* rows = ws + BL + 16;
    fb_qnorm<<<dim3(BL), 128, 0, stream>>>(clip, invq);
    mcount_kernel<<<dim3(BB), 256, 0, stream>>>(mask, mcnt);
    fb_main<<<dim3(LL / TI, BB), 256, 0, stream>>>(embs, clip, invq, mcnt, rows);
    fb_finalize<<<1, 256, 0, stream>>>(rows, mcnt, out);
  }
}

// Round 13
// 52.151 us; speedup vs baseline: 2.0828x; 2.0828x over previous
//
#include <hip/hip_runtime.h>
#include <hip/hip_bf16.h>

#define BB 16
#define LL 2048
#define DD 512
#define BL (BB*LL)
#define RADIUS 15
#define CF 1.25331414f   /* sqrt(2*pi)/2 */
#define NSL 5            /* j-slices: live = 16*5*~16 = ~1280 <= 1536 resident */
#define NII 32           /* 64-row i-tile slots (dead ones exit fast) */

typedef __attribute__((ext_vector_type(8))) short short8_t;
typedef __attribute__((ext_vector_type(4))) float f32x4;

static __device__ __forceinline__ unsigned short f2bf(float x){
  unsigned int u = __float_as_uint(x);
  return (unsigned short)((u + 0x7fffu + ((u >> 16) & 1u)) >> 16);  // RNE
}

static __device__ __forceinline__ void gld_lds16(const void* g, void* l){
  __builtin_amdgcn_global_load_lds(
      (const __attribute__((address_space(1))) unsigned int*)g,
      (__attribute__((address_space(3))) unsigned int*)l, 16, 0, 0);
}

// ---- f32 -> fp8 e4m3fn (OCP), RNE, saturating ----
#if __has_builtin(__builtin_amdgcn_cvt_pk_fp8_f32)
static __device__ __forceinline__ long f2fp8x8(float4 x0, float4 x1){
  int w0 = __builtin_amdgcn_cvt_pk_fp8_f32(x0.x, x0.y, 0, false);
  w0     = __builtin_amdgcn_cvt_pk_fp8_f32(x0.z, x0.w, w0, true);
  int w1 = __builtin_amdgcn_cvt_pk_fp8_f32(x1.x, x1.y, 0, false);
  w1     = __builtin_amdgcn_cvt_pk_fp8_f32(x1.z, x1.w, w1, true);
  return ((long)(unsigned)w1 << 32) | (unsigned)w0;
}
#else
static __device__ __forceinline__ unsigned f2fp8_1(float xf){
  unsigned x = __float_as_uint(xf);
  unsigned s = (x >> 24) & 0x80u;
  unsigned ax = x & 0x7fffffffu;
  if (ax >= 0x43e80000u) return s | 0x7eu;
  if (ax <  0x3a800000u) return s;
  unsigned exp = ax >> 23;
  if (exp <= 120){
    unsigned man = (ax & 0x7fffffu) | 0x800000u;
    int rsh = 141 - (int)exp;
    unsigned keep = man >> rsh;
    unsigned rem  = man & ((1u << rsh) - 1u);
    unsigned half = 1u << (rsh - 1);
    keep += (rem > half || (rem == half && (keep & 1u)));
    return s | keep;
  }
  unsigned keep = ax >> 20;
  unsigned rem  = ax & 0xfffffu;
  keep += (rem > 0x80000u || (rem == 0x80000u && (keep & 1u)));
  int code = (int)keep - (120 << 3);
  if (code >= 0x7f) code = 0x7e;
  return s | (unsigned)code;
}
static __device__ __forceinline__ long f2fp8x8(float4 x0, float4 x1){
  unsigned long o = 0;
  o |= (unsigned long)f2fp8_1(x0.x);
  o |= (unsigned long)f2fp8_1(x0.y) << 8;
  o |= (unsigned long)f2fp8_1(x0.z) << 16;
  o |= (unsigned long)f2fp8_1(x0.w) << 24;
  o |= (unsigned long)f2fp8_1(x1.x) << 32;
  o |= (unsigned long)f2fp8_1(x1.y) << 40;
  o |= (unsigned long)f2fp8_1(x1.z) << 48;
  o |= (unsigned long)f2fp8_1(x1.w) << 56;
  return (long)o;
}
#endif

// ============================ fast path (fp8) ============================
// p8 / q8 fragment-major per batch, BANK-SWIZZLED:
//   chunk(kb, row16tile) = 512 B at  b*LL*DD + (kb*LL + tile*16)*32
//   within chunk: (row r, group kg) -> (r&15)*32 + (kg ^ ((r>>2)&3))*8
// reader lane (col,kg) uses byte col*32 + (kg^(col>>2))*8 -> uniform 2/bank.

__global__ void mcount_kernel(const int* __restrict__ mask, int* __restrict__ mout){
  int b = blockIdx.x;
  int s = 0;
  for (int j = threadIdx.x; j < LL; j += 256) s += (mask[(size_t)b*LL + j] > 0) ? 1 : 0;
  __shared__ int sred[256];
  sred[threadIdx.x] = s; __syncthreads();
  for (int k = 128; k; k >>= 1){
    if (threadIdx.x < k) sred[threadIdx.x] += sred[threadIdx.x + k];
    __syncthreads();
  }
  if (threadIdx.x == 0) mout[b] = sred[0];
}

// normalize rows -> fp8 fragment-major (swizzled); skip rows >= ceil(M/128)*128
// (round-7 version: part of the proven 54.1us build)
__global__ __launch_bounds__(256) void precvt(const float* __restrict__ embs,
                                              const float* __restrict__ clip,
                                              const int* __restrict__ mcnt,
                                              unsigned char* __restrict__ p8,
                                              unsigned char* __restrict__ q8){
  const int lane = threadIdx.x & 63;
  for (int gw = blockIdx.x * 4 + (threadIdx.x >> 6); gw < 2 * BL; gw += 4096 * 4){
    const float* src; unsigned char* dst; int r, b;
    if (gw < BL){ b = gw >> 11; r = gw & 2047; src = embs + (size_t)gw * DD;
                  dst = p8 + (size_t)b * LL * DD; }
    else { int g = gw - BL; b = g >> 11; r = g & 2047; src = clip + (size_t)g * DD;
           dst = q8 + (size_t)b * LL * DD; }
    const int RND = (mcnt[b] + 127) & ~127;
    if (r >= RND) continue;
    float4 x0 = *(const float4*)(src + lane * 8);
    float4 x1 = *(const float4*)(src + lane * 8 + 4);
    float ss = x0.x*x0.x + x0.y*x0.y + x0.z*x0.z + x0.w*x0.w
             + x1.x*x1.x + x1.y*x1.y + x1.z*x1.z + x1.w*x1.w;
    #pragma unroll
    for (int m = 1; m < 64; m <<= 1) ss += __shfl_xor(ss, m, 64);
    float s = 1.0f / fmaxf(sqrtf(ss), 1e-12f);
    float4 y0 = make_float4(x0.x*s, x0.y*s, x0.z*s, x0.w*s);
    float4 y1 = make_float4(x1.x*s, x1.y*s, x1.z*s, x1.w*s);
    long o = f2fp8x8(y0, y1);
    const int kswz = (lane & 3) ^ ((r >> 2) & 3);
    *(long*)(dst + ((size_t)((lane >> 2) * LL + r) << 5) + (kswz << 3)) = o;
  }
}

// 4 waves/block, ONE 64-row i-tile (16 rows/wave, single stripe);
// 3x8KB LDS B-tiles, counted-vmcnt pipeline; ~6 blocks/CU for TLP.
__global__ __launch_bounds__(256, 6) void gram12(
    const unsigned char* __restrict__ p8, const unsigned char* __restrict__ q8,
    const int* __restrict__ mcnt, float* __restrict__ part /* [BB][LL][NSL] float4 */)
{
  const int bid = blockIdx.x;                 // 16 * NSL * NII = 2560
  const int xcd = bid & 7;
  const int b   = (xcd << 1) | ((bid >> 3) & 1);   // batch pinned to XCD
  const int ii  = (bid >> 4) & (NII - 1);          // 64-row i-tile (fast-varying)
  const int js  = bid >> 9;                        // j-slice [0,NSL)
  const int M   = mcnt[b];
  const int nIt = (M + 63) >> 6;                   // 64-row i-tiles
  if (ii >= nIt) return;                           // dead block: exits fast

  __shared__ alignas(16) unsigned char bsm[3][8192];   // 3 x 8 KB fp8 B-tiles
  __shared__ float gt[RADIUS + 1];

  const int tid  = threadIdx.x;
  const int wave = tid >> 6;
  const int lane = tid & 63;
  const int col  = lane & 15;
  const int kg   = lane >> 4;
  const int kswz = (kg ^ (col >> 2)) << 3;     // bank-swizzled 8B slot

  if (tid <= RADIUS)
    gt[tid] = expm1f(CF * __expf(-(float)(tid * tid) * 0.125f));
  __syncthreads();

  const unsigned char* pb = p8 + (size_t)b * LL * DD;
  const unsigned char* qb = q8 + (size_t)b * LL * DD;
  const int njt = (M + 15) >> 4;
  const int S   = (njt > js) ? ((njt - js + NSL - 1) / NSL) : 0;
  if (S == 0) return;

  #define STAGE(BF, JT) do {                                                     \
    const int _j0 = (JT) << 4;                                                   \
    _Pragma("unroll")                                                            \
    for (int u = 0; u < 2; ++u){                                                 \
      const int _kb0 = (wave << 1) + (u << 3);                                   \
      gld_lds16(qb + ((size_t)((_kb0 + (lane >> 5)) * LL + _j0) << 5)            \
                   + ((lane & 31) << 4),                                         \
                (void*)&bsm[BF][_kb0 << 9]);                                     \
    }                                                                            \
  } while (0)

  const int iw = (ii << 6) + (wave << 4);      // this wave's 16-row stripe base

  // A fragments: 1 stripe x 16 kb, 2 VGPRs each = 32 regs
  long a0[16];
  #pragma unroll
  for (int kb = 0; kb < 16; ++kb)
    a0[kb] = *(const long*)(pb + ((size_t)(kb * LL + iw + col) << 5) + kswz);
  // opaque pin (proven r8 pattern): keep A live across the j-loop
  #pragma unroll
  for (int kb = 0; kb < 16; ++kb) asm volatile("" : "+v"(a0[kb]));

  float es0[4]={0,0,0,0}, ls0[4]={0,0,0,0}, bg0[4]={0,0,0,0};

  STAGE(0, js);
  if (S > 1) STAGE(1, js + NSL);

  for (int s = 0; s < S; ++s){
    // own 2 loads for tile s retired; never drain to 0 mid-loop
    if (s + 1 < S) { asm volatile("s_waitcnt vmcnt(2)" ::: "memory"); }
    else           { asm volatile("s_waitcnt vmcnt(0)" ::: "memory"); }
    __builtin_amdgcn_s_barrier();
    __builtin_amdgcn_sched_barrier(0);
    if (s + 2 < S) STAGE((s + 2) % 3, js + NSL * (s + 2));

    const int j0 = (js + NSL * s) << 4;
    f32x4 c0 = {0.f,0.f,0.f,0.f};
    const unsigned char* lb = &bsm[s % 3][(col << 5) + kswz];
    #pragma unroll
    for (int kb = 0; kb < 16; ++kb){
      long bf8 = *(const long*)(lb + (kb << 9));    // ds_read_b64, 2/bank
      c0 = __builtin_amdgcn_mfma_f32_16x16x32_fp8_fp8(a0[kb], bf8, c0, 0, 0, 0);
    }
    const int j = j0 + col;
    if (j < M){
      const int dt0 = j - iw - (kg << 2);
      #pragma unroll
      for (int r = 0; r < 4; ++r){
        float lg = c0[r];                      // logits[iw + kg*4 + r][j]
        es0[r] += __expf(lg); ls0[r] += lg;
        int d = dt0 - r; int ad = d < 0 ? -d : d;
        if (ad <= RADIUS) bg0[r] += gt[ad] * lg;
      }
    }
  }
  #undef STAGE

  #pragma unroll
  for (int m = 1; m < 16; m <<= 1){
    #pragma unroll
    for (int r = 0; r < 4; ++r){
      es0[r] += __shfl_xor(es0[r], m, 64);
      ls0[r] += __shfl_xor(ls0[r], m, 64);
      bg0[r] += __shfl_xor(bg0[r], m, 64);
    }
  }
  if (col == 0){
    #pragma unroll
    for (int r = 0; r < 4; ++r){
      int ia = iw + (kg << 2) + r;
      *(float4*)&part[(((size_t)b * LL + ia) * NSL + js) * 4] =
          make_float4(es0[r], ls0[r], bg0[r], 0.f);
    }
  }
}

// per-batch row-sum epilogue with analytic Zt/U prefix tables
__global__ __launch_bounds__(256) void finalize1(const float* __restrict__ part,
                                                 const int* __restrict__ mcnt,
                                                 float* __restrict__ psum){
  const int b = blockIdx.x;
  const int M = mcnt[b];
  __shared__ float e1s[16], tts[16], S1[16], TT[16], red[256];
  const int tid = threadIdx.x;
  if (tid < 16){
    float u  = CF * __expf(-(float)(tid * tid) * 0.125f);
    float eu = __expf(u);
    e1s[tid] = eu - 1.0f;
    tts[tid] = u * eu;
  }
  __syncthreads();
  if (tid == 0){
    float a = 0.f, c = 0.f;
    S1[0] = 0.f; TT[0] = 0.f;
    for (int d = 1; d <= RADIUS; ++d){ a += e1s[d]; c += tts[d]; S1[d] = a; TT[d] = c; }
  }
  __syncthreads();
  const float e10 = e1s[0], tt0 = tts[0];
  float acc = 0.f;
  for (int i = tid; i < M; i += 256){
    float es = 0.f, ls = 0.f, bg = 0.f;
    #pragma unroll
    for (int h = 0; h < NSL; ++h){
      float4 v = *(const float4*)&part[(((size_t)b * LL + i) * NSL + h) * 4];
      es += v.x; ls += v.y; bg += v.z;
    }
    int rl = i < RADIUS ? i : RADIUS;
    int rr = (M - 1 - i) < RADIUS ? (M - 1 - i) : RADIUS;
    float Zt = (float)M + e10 + S1[rl] + S1[rr];
    float U  = tt0 + TT[rl] + TT[rr];
    acc += (U - ls - bg) / Zt + logf(es) - logf(Zt);
  }
  red[tid] = acc; __syncthreads();
  for (int k = 128; k; k >>= 1){
    if (tid < k) red[tid] += red[tid + k];
    __syncthreads();
  }
  if (tid == 0) psum[b] = red[0] / (float)M;
}

__global__ void finalize2(const float* __restrict__ psum, float* __restrict__ out){
  if (threadIdx.x == 0){
    float a = 0.f;
    for (int b = 0; b < BB; ++b) a += psum[b];
    out[0] = a / (float)BB;
  }
}

// ======================= fallback path (round-1, known good) =======================
#define TI 32
#define TJ 32
#define LSTR 520

__global__ void fb_qnorm(const float* __restrict__ clip, float* __restrict__ invq){
  int row = blockIdx.x;
  const float* p = clip + (size_t)row * DD;
  float4 v = *(const float4*)(p + (threadIdx.x << 2));
  float ss = v.x*v.x + v.y*v.y + v.z*v.z + v.w*v.w;
  for (int m = 32; m; m >>= 1) ss += __shfl_down(ss, m, 64);
  __shared__ float red[2];
  if ((threadIdx.x & 63) == 0) red[threadIdx.x >> 6] = ss;
  __syncthreads();
  if (threadIdx.x == 0)
    invq[row] = 1.0f / fmaxf(sqrtf(red[0] + red[1]), 1e-12f);
}

__global__ __launch_bounds__(256) void fb_main(
    const float* __restrict__ embs, const float* __restrict__ clip,
    const float* __restrict__ invq, const int* __restrict__ mcnt,
    float* __restrict__ row_sums)
{
  const int b  = blockIdx.y;
  const int M  = mcnt[b];
  const int i0 = blockIdx.x * TI;
  if (i0 >= M) return;
  __shared__ alignas(16) unsigned short qlds[TJ * LSTR];
  __shared__ float gtab[RADIUS + 1];
  __shared__ float partials[2][TI][3];
  const int tid  = threadIdx.x;
  const int wave = tid >> 6;
  const int lane = tid & 63;
  const int col  = lane & 15;
  const int kg   = lane >> 4;
  const int isub = wave >> 1;
  const int jsub = wave & 1;
  const int iw   = i0 + isub * 16;
  if (tid <= RADIUS)
    gtab[tid] = expm1f(CF * expf(-(float)(tid * tid) * 0.125f));
  const int arow = iw + col;
  const float* prow = embs + ((size_t)b * LL + arow) * DD;
  float ss = 0.f;
  for (int kb = 0; kb < 16; ++kb){
    float4 x0 = *(const float4*)(prow + kb * 32 + kg * 8);
    float4 x1 = *(const float4*)(prow + kb * 32 + kg * 8 + 4);
    ss += x0.x*x0.x + x0.y*x0.y + x0.z*x0.z + x0.w*x0.w
        + x1.x*x1.x + x1.y*x1.y + x1.z*x1.z + x1.w*x1.w;
  }
  ss += __shfl_xor(ss, 16, 64);
  ss += __shfl_xor(ss, 32, 64);
  const float sp = 1.0f / fmaxf(sqrtf(ss), 1e-12f);
  short8_t afrag[16];
  for (int kb = 0; kb < 16; ++kb){
    float4 x0 = *(const float4*)(prow + kb * 32 + kg * 8);
    float4 x1 = *(const float4*)(prow + kb * 32 + kg * 8 + 4);
    short8_t f;
    f[0]=(short)f2bf(x0.x*sp); f[1]=(short)f2bf(x0.y*sp);
    f[2]=(short)f2bf(x0.z*sp); f[3]=(short)f2bf(x0.w*sp);
    f[4]=(short)f2bf(x1.x*sp); f[5]=(short)f2bf(x1.y*sp);
    f[6]=(short)f2bf(x1.z*sp); f[7]=(short)f2bf(x1.w*sp);
    afrag[kb] = f;
  }
  float es[4]={0,0,0,0}, lsm[4]={0,0,0,0}, bg[4]={0,0,0,0};
  const int nj = (M + TJ - 1) / TJ;
  for (int jt = 0; jt < nj; ++jt){
    const int jb = jt * TJ;
    __syncthreads();
    {
      const float* qbase = clip + ((size_t)b * LL + jb) * DD;
      for (int u = 0; u < 16; ++u){
        int f  = u * 256 + tid;
        int r  = f >> 7, c4 = f & 127;
        int j  = jb + r;
        ushort4 wv = make_ushort4(0,0,0,0);
        if (j < M){
          float s = invq[b * LL + j];
          float4 x = *(const float4*)(qbase + ((size_t)r << 9) + (c4 << 2));
          wv = make_ushort4(f2bf(x.x*s), f2bf(x.y*s), f2bf(x.z*s), f2bf(x.w*s));
        }
        *reinterpret_cast<ushort4*>(&qlds[r * LSTR + (c4 << 2)]) = wv;
      }
    }
    __syncthreads();
    const int j0 = jb + jsub * 16;
    f32x4 acc = {0.f,0.f,0.f,0.f};
    const unsigned short* bbase = &qlds[(jsub * 16 + col) * LSTR + kg * 8];
    #pragma unroll
    for (int kb = 0; kb < 16; ++kb){
      short8_t bfrag = *reinterpret_cast<const short8_t*>(bbase + kb * 32);
      acc = __builtin_amdgcn_mfma_f32_16x16x32_bf16(afrag[kb], bfrag, acc, 0, 0, 0);
    }
    const int j = j0 + col;
    if (j < M){
      const int dt = j - iw - kg * 4;
      #pragma unroll
      for (int r = 0; r < 4; ++r){
        float lg = acc[r];
        es[r]  += expf(lg);
        lsm[r] += lg;
        int d = dt - r; int ad = d < 0 ? -d : d;
        if (ad <= RADIUS) bg[r] += gtab[ad] * lg;
      }
    }
  }
  #pragma unroll
  for (int m = 1; m < 16; m <<= 1){
    #pragma unroll
    for (int r = 0; r < 4; ++r){
      es[r]  += __shfl_xor(es[r],  m, 64);
      lsm[r] += __shfl_xor(lsm[r], m, 64);
      bg[r]  += __shfl_xor(bg[r],  m, 64);
    }
  }
  if (col == 0){
    #pragma unroll
    for (int r = 0; r < 4; ++r){
      int lrow = isub * 16 + kg * 4 + r;
      partials[jsub][lrow][0] = es[r];
      partials[jsub][lrow][1] = lsm[r];
      partials[jsub][lrow][2] = bg[r];
    }
  }
  __syncthreads();
  if (tid < TI){
    int i = i0 + tid;
    if (i < M){
      float esf = partials[0][tid][0] + partials[1][tid][0];
      float lsf = partials[0][tid][1] + partials[1][tid][1];
      float bgf = partials[0][tid][2] + partials[1][tid][2];
      int dlo = (-RADIUS < -i) ? -i : -RADIUS;
      int dhi = (RADIUS > M - 1 - i) ? (M - 1 - i) : RADIUS;
      float Zt = (float)M, U = 0.f;
      for (int d = dlo; d <= dhi; ++d){
        float uu = CF * expf(-(float)(d * d) * 0.125f);
        float eu = expf(uu);
        Zt += eu - 1.0f;
        U  += uu * eu;
      }
      row_sums[(size_t)b * LL + i] = (U - lsf - bgf) / Zt + logf(esf / Zt);
    }
  }
}

__global__ void fb_finalize(const float* __restrict__ row_sums,
                            const int* __restrict__ mcnt, float* __restrict__ out){
  __shared__ float red[256];
  float acc = 0.f;
  for (int b = 0; b < BB; ++b){
    int M = mcnt[b];
    float s = 0.f;
    for (int i = threadIdx.x; i < M; i += 256) s += row_sums[(size_t)b * LL + i];
    red[threadIdx.x] = s; __syncthreads();
    for (int k = 128; k; k >>= 1){
      if (threadIdx.x < k) red[threadIdx.x] += red[threadIdx.x + k];
      __syncthreads();
    }
    if (threadIdx.x == 0) acc += red[0] / (float)M;
    __syncthreads();
  }
  if (threadIdx.x == 0) out[0] = acc / (float)BB;
}

// ================================ launch ================================

extern "C" void kernel_launch(void* const* d_in, const int* in_sizes, int n_in,
                              void* d_out, int out_size, void* d_ws, size_t ws_size,
                              hipStream_t stream) {
  const float* embs = (const float*)d_in[0];
  const float* clip = (const float*)d_in[1];
  const int*   mask = (const int*)d_in[2];
  float* out = (float*)d_out;

  const size_t REQ = (size_t)2 * BL * DD                              // p8 + q8 (fp8)
                   + (size_t)BB * LL * NSL * 4 * sizeof(float)        // partials
                   + 64 * sizeof(float);                              // psum + mcnt
  if (ws_size >= REQ){
    unsigned char* p8 = (unsigned char*)d_ws;
    unsigned char* q8 = p8 + (size_t)BL * DD;
    float* part = (float*)(q8 + (size_t)BL * DD);
    float* psum = part + (size_t)BB * LL * NSL * 4;
    int*   mcnt = (int*)(psum + 16);

    mcount_kernel<<<dim3(BB), 256, 0, stream>>>(mask, mcnt);
    precvt<<<dim3(4096), 256, 0, stream>>>(embs, clip, mcnt, p8, q8);
    gram12<<<dim3(16 * NSL * NII), 256, 0, stream>>>(p8, q8, mcnt, part);
    finalize1<<<dim3(BB), 256, 0, stream>>>(part, mcnt, psum);
    finalize2<<<1, 64, 0, stream>>>(psum, out);
  } else {
    float* ws   = (float*)d_ws;
    float* invq = ws;
    int*   mcnt = (int*)(ws + BL);
    float* rows = ws + BL + 16;
    fb_qnorm<<<dim3(BL), 128, 0, stream>>>(clip, invq);
    mcount_kernel<<<dim3(BB), 256, 0, stream>>>(mask, mcnt);
    fb_main<<<dim3(LL / TI, BB), 256, 0, stream>>>(embs, clip, invq, mcnt, rows);
    fb_finalize<<<1, 256, 0, stream>>>(rows, mcnt, out);
  }
}